// Round 1
// baseline (1875.732 us; speedup 1.0000x reference)
//
#include <hip/hip_runtime.h>

// ---------------------------------------------------------------------------
// degree kernels
// ---------------------------------------------------------------------------
__global__ __launch_bounds__(256) void deg_init_k(float* __restrict__ deg, int n) {
    int i = blockIdx.x * 256 + threadIdx.x;
    if (i < n) deg[i] = 1.0f;   // self-loop
}

__global__ __launch_bounds__(256) void deg_hist_k(const int* __restrict__ di,
                                                  float* __restrict__ deg, int ne) {
    int i = blockIdx.x * 256 + threadIdx.x;
    if (i < ne) atomicAdd(deg + di[i], 1.0f);
}

__global__ __launch_bounds__(256) void deg_rsqrt_k(float* __restrict__ deg, int n) {
    int i = blockIdx.x * 256 + threadIdx.x;
    if (i < n) deg[i] = 1.0f / sqrtf(deg[i]);
}

// ---------------------------------------------------------------------------
// embedding: f[n,p] = sum_q ( w[q]*S[p,q]/||w*S[:,q]|| + G[p,q]/||G[:,q]|| )
//   S[p,q] = src_emb[src[n,p], q],  G[p,q] = seg_emb[seg[n,p], q]
// one 64-lane wave per node; 64x64 tile in LDS with stride 65 (2-way banks = free)
// ---------------------------------------------------------------------------
__global__ __launch_bounds__(64) void embed_k(
    const int* __restrict__ src, const int* __restrict__ seg,
    const float* __restrict__ src_emb, const float* __restrict__ seg_emb,
    const float* __restrict__ w, float* __restrict__ f)
{
    __shared__ float S[64 * 65];
    __shared__ float rS[64];
    __shared__ float rGl[64];
    __shared__ float segE[3 * 64];
    __shared__ float dG[3];

    const int q = threadIdx.x;          // lane = column q
    const int n = blockIdx.x;

    // seg_emb is 3x64: lane q stages exactly the elements it will read back
    segE[q]       = seg_emb[q];
    segE[64 + q]  = seg_emb[64 + q];
    segE[128 + q] = seg_emb[128 + q];

    const float wq = w[q];
    const int sidx = src[(long)n * 64 + q];   // token index held by lane q
    const int gidx = seg[(long)n * 64 + q];

    float s2 = 0.f, g2 = 0.f;
    #pragma unroll 8
    for (int p = 0; p < 64; ++p) {
        int idx = __shfl(sidx, p);            // broadcast token p's vocab id
        float v = wq * src_emb[(long)idx * 64 + q];   // coalesced 256B row read
        S[p * 65 + q] = v;
        s2 += v * v;
        int sc = __shfl(gidx, p);
        float gv = segE[sc * 64 + q];
        g2 += gv * gv;
    }
    rS[q]  = 1.0f / fmaxf(sqrtf(s2), 1e-12f);
    rGl[q] = 1.0f / fmaxf(sqrtf(g2), 1e-12f);
    __syncthreads();

    if (q < 3) {
        float acc = 0.f;
        for (int k = 0; k < 64; ++k) acc += segE[q * 64 + k] * rGl[k];
        dG[q] = acc;
    }
    __syncthreads();

    // stage 2: lane takes role p = q (row of the tile)
    float acc = 0.f;
    #pragma unroll 8
    for (int k = 0; k < 64; ++k) acc += S[q * 65 + k] * rS[k];
    acc += dG[gidx];
    f[(long)n * 64 + q] = acc;
}

// ---------------------------------------------------------------------------
// fused 2-layer MLP: out = relu(f @ W1 + b1) @ W2 + b2     (64 ->128 -> 64)
// 16 rows per 256-thread block; W1 in LDS; W2 via L1 (exactly 32 KiB, hot)
// ---------------------------------------------------------------------------
__global__ __launch_bounds__(256) void mlp2(
    const float* __restrict__ f,
    const float* __restrict__ W1, const float* __restrict__ b1,
    const float* __restrict__ W2, const float* __restrict__ b2,
    float* __restrict__ out, int nrows)
{
    __shared__ float Wl[64 * 128];
    __shared__ float F[16 * 64];
    __shared__ float H[16 * 128];
    const int t = threadIdx.x;
    for (int i = t; i < 64 * 128; i += 256) Wl[i] = W1[i];
    const int row0 = blockIdx.x * 16;
    for (int i = t; i < 16 * 64; i += 256) {
        int r = i >> 6;
        F[i] = (row0 + r < nrows) ? f[(long)row0 * 64 + i] : 0.f;
    }
    __syncthreads();
    {
        const int r = t >> 7, j = t & 127;
        const float b = b1[j];
        for (int rr = r; rr < 16; rr += 2) {
            float acc = b;
            #pragma unroll 16
            for (int k = 0; k < 64; ++k) acc += F[rr * 64 + k] * Wl[k * 128 + j];
            H[rr * 128 + j] = fmaxf(acc, 0.f);
        }
    }
    __syncthreads();
    {
        const int r = t >> 6, j = t & 63;
        const float b = b2[j];
        for (int rr = r; rr < 16; rr += 4) {
            float acc = b;
            #pragma unroll 16
            for (int k = 0; k < 128; ++k) acc += H[rr * 128 + k] * W2[k * 64 + j];
            if (row0 + rr < nrows) out[(long)(row0 + rr) * 64 + j] = acc;
        }
    }
}

// ---------------------------------------------------------------------------
// generic row-tile GEMM: out[r,j] = (optional out_bias[j]) +
//                        sum_k T(in[r,k]) * W[k,j],  T = relu(x + in_bias) if IN_RELU
// ---------------------------------------------------------------------------
template <int KD, int JD, bool IN_RELU>
__global__ __launch_bounds__(256) void gemm_rt(
    const float* __restrict__ in, const float* __restrict__ W,
    const float* __restrict__ in_bias, const float* __restrict__ out_bias,
    float* __restrict__ out, int nrows)
{
    __shared__ float Wl[KD * JD];
    __shared__ float F[16 * KD];
    const int t = threadIdx.x;
    for (int i = t; i < KD * JD; i += 256) Wl[i] = W[i];
    const int row0 = blockIdx.x * 16;
    for (int i = t; i < 16 * KD; i += 256) {
        int r = i / KD, k = i % KD;     // KD is a power of two -> shifts
        float v = 0.f;
        if (row0 + r < nrows) {
            v = in[(long)(row0 + r) * KD + k];
            if (IN_RELU) v = fmaxf(v + in_bias[k], 0.f);
        }
        F[i] = v;
    }
    __syncthreads();
    constexpr int RPF = 256 / JD;
    const int r = t / JD, j = t % JD;
    const float ob = out_bias ? out_bias[j] : 0.f;
    for (int rr = r; rr < 16; rr += RPF) {
        float acc = ob;
        #pragma unroll 16
        for (int k = 0; k < KD; ++k) acc += F[rr * KD + k] * Wl[k * JD + j];
        if (row0 + rr < nrows) out[(long)(row0 + rr) * JD + j] = acc;
    }
}

// ---------------------------------------------------------------------------
// GCN aggregation
// ---------------------------------------------------------------------------
template <int H>
__global__ __launch_bounds__(256) void self_init_k(
    const float* __restrict__ h, const float* __restrict__ dinv,
    float* __restrict__ o, int n)
{
    long tid = (long)blockIdx.x * 256 + threadIdx.x;
    if (tid >= (long)n * H) return;
    int node = (int)(tid / H);
    float d = dinv[node];
    o[tid] = h[tid] * d * d;
}

template <int H>
__global__ __launch_bounds__(256) void scatter_k(
    const float* __restrict__ h, float* __restrict__ o,
    const int* __restrict__ si, const int* __restrict__ di,
    const float* __restrict__ dinv, int ne)
{
    constexpr int JP = H / 4;             // float4 per thread
    long tid = (long)blockIdx.x * 256 + threadIdx.x;
    if (tid >= (long)ne * JP) return;
    int e  = (int)(tid / JP);
    int jq = ((int)(tid % JP)) * 4;
    int s = si[e], d = di[e];
    float nm = dinv[s] * dinv[d];
    const float4 v = *(const float4*)(h + (long)s * H + jq);
    float* op = o + (long)d * H + jq;
    atomicAdd(op + 0, v.x * nm);
    atomicAdd(op + 1, v.y * nm);
    atomicAdd(op + 2, v.z * nm);
    atomicAdd(op + 3, v.w * nm);
}

// ---------------------------------------------------------------------------
extern "C" void kernel_launch(void* const* d_in, const int* in_sizes, int n_in,
                              void* d_out, int out_size, void* d_ws, size_t ws_size,
                              hipStream_t stream) {
    const int*   src     = (const int*)  d_in[0];
    const int*   seg     = (const int*)  d_in[1];
    const int*   ei      = (const int*)  d_in[2];
    const float* src_emb = (const float*)d_in[3];
    const float* seg_emb = (const float*)d_in[4];
    const float* w       = (const float*)d_in[5];
    const float* Wq1     = (const float*)d_in[6];
    const float* bq1     = (const float*)d_in[7];
    const float* Wq2     = (const float*)d_in[8];
    const float* bq2     = (const float*)d_in[9];
    const float* Wg1     = (const float*)d_in[10];
    const float* bg1     = (const float*)d_in[11];
    const float* Wg2     = (const float*)d_in[12];
    const float* bg2     = (const float*)d_in[13];
    const float* Wl      = (const float*)d_in[14];
    const float* bl      = (const float*)d_in[15];
    float* out = (float*)d_out;

    const int N  = in_sizes[0] / 64;
    const int NE = in_sizes[2] / 2;
    const int* si = ei;
    const int* di = ei + NE;

    // workspace layout (f32): dinv[N] | f[N*64] | h1[N*128] | o1[N*128]
    // h2 aliases f (f/x dead by then), o2 aliases h1 (dead after scatter1)
    float* ws   = (float*)d_ws;
    float* dinv = ws;
    float* f    = ws + N;
    float* h1   = f  + (size_t)N * 64;
    float* o1   = h1 + (size_t)N * 128;
    float* x    = f;    // mlp2 runs in place (per-block row tile, read-then-write)
    float* h2   = f;
    float* o2   = h1;

    dim3 b256(256);
    deg_init_k <<<(N  + 255) / 256, b256, 0, stream>>>(dinv, N);
    deg_hist_k <<<(NE + 255) / 256, b256, 0, stream>>>(di, dinv, NE);
    deg_rsqrt_k<<<(N  + 255) / 256, b256, 0, stream>>>(dinv, N);

    embed_k<<<N, 64, 0, stream>>>(src, seg, src_emb, seg_emb, w, f);

    const int gBlocks = (N + 15) / 16;
    mlp2<<<gBlocks, b256, 0, stream>>>(f, Wq1, bq1, Wq2, bq2, x, N);

    // GCN layer 1: h1 = x @ Wg1 ; o1 = agg + self ; (bias+relu folded into next gemm)
    gemm_rt<64, 128, false><<<gBlocks, b256, 0, stream>>>(x, Wg1, nullptr, nullptr, h1, N);
    self_init_k<128><<<(int)(((long)N * 128 + 255) / 256), b256, 0, stream>>>(h1, dinv, o1, N);
    scatter_k<128><<<(int)(((long)NE * 32 + 255) / 256), b256, 0, stream>>>(h1, o1, si, di, dinv, NE);

    // GCN layer 2: h2 = relu(o1 + bg1) @ Wg2 ; o2 = agg + self
    gemm_rt<128, 64, true><<<gBlocks, b256, 0, stream>>>(o1, Wg2, bg1, nullptr, h2, N);
    self_init_k<64><<<(int)(((long)N * 64 + 255) / 256), b256, 0, stream>>>(h2, dinv, o2, N);
    scatter_k<64><<<(int)(((long)NE * 16 + 255) / 256), b256, 0, stream>>>(h2, o2, si, di, dinv, NE);

    // output: out = relu(o2 + bg2) @ Wl + bl
    gemm_rt<64, 64, true><<<gBlocks, b256, 0, stream>>>(o2, Wl, bg2, bl, out, N);
}

// Round 2
// 435.514 us; speedup vs baseline: 4.3069x; 4.3069x over previous
//
#include <hip/hip_runtime.h>

// ---------------------------------------------------------------------------
// CSR build: count -> scan(+dinv,+cursor) -> fill
// ---------------------------------------------------------------------------
__global__ __launch_bounds__(256) void zero_int_k(int* __restrict__ p, int n) {
    int i = blockIdx.x * 256 + threadIdx.x;
    if (i < n) p[i] = 0;
}

__global__ __launch_bounds__(256) void count_k(const int* __restrict__ di,
                                               int* __restrict__ cnt, int ne) {
    int i = blockIdx.x * 256 + threadIdx.x;
    if (i < ne) atomicAdd(cnt + di[i], 1);
}

// single block, 1024 threads: exclusive scan of cnt -> row_ptr, cursor copy,
// dinv[i] = rsqrt(cnt[i]+1)
__global__ __launch_bounds__(1024) void scan_k(const int* __restrict__ cnt,
                                               int* __restrict__ row_ptr,
                                               int* __restrict__ cursor,
                                               float* __restrict__ dinv,
                                               int n, int ne) {
    __shared__ int sums[1024];
    const int t = threadIdx.x;
    const int C = (n + 1023) >> 10;          // elems per thread
    const int start = t * C;
    const int end   = min(start + C, n);
    int s = 0;
    for (int i = start; i < end; ++i) s += cnt[i];
    sums[t] = s;
    __syncthreads();
    for (int off = 1; off < 1024; off <<= 1) {
        int v = sums[t];
        int add = (t >= off) ? sums[t - off] : 0;
        __syncthreads();
        sums[t] = v + add;
        __syncthreads();
    }
    int run = sums[t] - s;                   // exclusive prefix of this chunk
    for (int i = start; i < end; ++i) {
        int c = cnt[i];
        row_ptr[i] = run;
        cursor[i]  = run;
        dinv[i]    = rsqrtf((float)c + 1.0f);
        run += c;
    }
    if (t == 0) row_ptr[n] = ne;
}

__global__ __launch_bounds__(256) void fill_k(const int* __restrict__ si,
                                              const int* __restrict__ di,
                                              int* __restrict__ cursor,
                                              int* __restrict__ edge_src, int ne) {
    int i = blockIdx.x * 256 + threadIdx.x;
    if (i < ne) {
        int pos = atomicAdd(cursor + di[i], 1);
        edge_src[pos] = si[i];
    }
}

// ---------------------------------------------------------------------------
// embedding: f[n,p] = sum_q ( w[q]*S[p,q]/||w*S[:,q]|| + G[p,q]/||G[:,q]|| )
// one 64-lane wave per node; 64x64 tile in LDS with stride 65
// ---------------------------------------------------------------------------
__global__ __launch_bounds__(64) void embed_k(
    const int* __restrict__ src, const int* __restrict__ seg,
    const float* __restrict__ src_emb, const float* __restrict__ seg_emb,
    const float* __restrict__ w, float* __restrict__ f)
{
    __shared__ float S[64 * 65];
    __shared__ float rS[64];
    __shared__ float rGl[64];
    __shared__ float segE[3 * 64];
    __shared__ float dG[3];

    const int q = threadIdx.x;          // lane = column q
    const int n = blockIdx.x;

    segE[q]       = seg_emb[q];
    segE[64 + q]  = seg_emb[64 + q];
    segE[128 + q] = seg_emb[128 + q];

    const float wq = w[q];
    const int sidx = src[(long)n * 64 + q];
    const int gidx = seg[(long)n * 64 + q];

    float s2 = 0.f, g2 = 0.f;
    #pragma unroll 8
    for (int p = 0; p < 64; ++p) {
        int idx = __shfl(sidx, p);
        float v = wq * src_emb[(long)idx * 64 + q];
        S[p * 65 + q] = v;
        s2 += v * v;
        int sc = __shfl(gidx, p);
        float gv = segE[sc * 64 + q];
        g2 += gv * gv;
    }
    rS[q]  = 1.0f / fmaxf(sqrtf(s2), 1e-12f);
    rGl[q] = 1.0f / fmaxf(sqrtf(g2), 1e-12f);
    __syncthreads();

    if (q < 3) {
        float acc = 0.f;
        for (int k = 0; k < 64; ++k) acc += segE[q * 64 + k] * rGl[k];
        dG[q] = acc;
    }
    __syncthreads();

    float acc = 0.f;
    #pragma unroll 8
    for (int k = 0; k < 64; ++k) acc += S[q * 65 + k] * rS[k];
    acc += dG[gidx];
    f[(long)n * 64 + q] = acc;
}

// ---------------------------------------------------------------------------
// fused 2-layer MLP: out = relu(f @ W1 + b1) @ W2 + b2     (64 ->128 -> 64)
// ---------------------------------------------------------------------------
__global__ __launch_bounds__(256) void mlp2(
    const float* __restrict__ f,
    const float* __restrict__ W1, const float* __restrict__ b1,
    const float* __restrict__ W2, const float* __restrict__ b2,
    float* __restrict__ out, int nrows)
{
    __shared__ float Wl[64 * 128];
    __shared__ float F[16 * 64];
    __shared__ float H[16 * 128];
    const int t = threadIdx.x;
    for (int i = t; i < 64 * 128; i += 256) Wl[i] = W1[i];
    const int row0 = blockIdx.x * 16;
    for (int i = t; i < 16 * 64; i += 256) {
        int r = i >> 6;
        F[i] = (row0 + r < nrows) ? f[(long)row0 * 64 + i] : 0.f;
    }
    __syncthreads();
    {
        const int r = t >> 7, j = t & 127;
        const float b = b1[j];
        for (int rr = r; rr < 16; rr += 2) {
            float acc = b;
            #pragma unroll 16
            for (int k = 0; k < 64; ++k) acc += F[rr * 64 + k] * Wl[k * 128 + j];
            H[rr * 128 + j] = fmaxf(acc, 0.f);
        }
    }
    __syncthreads();
    {
        const int r = t >> 6, j = t & 63;
        const float b = b2[j];
        for (int rr = r; rr < 16; rr += 4) {
            float acc = b;
            #pragma unroll 16
            for (int k = 0; k < 128; ++k) acc += H[rr * 128 + k] * W2[k * 64 + j];
            if (row0 + rr < nrows) out[(long)(row0 + rr) * 64 + j] = acc;
        }
    }
}

// ---------------------------------------------------------------------------
// row-tile GEMM with optional input relu(x+bias), output bias, per-row scale:
//   out[r,j] = rs[r] * ( ob[j] + sum_k T(in[r,k]) * W[k,j] )
// ---------------------------------------------------------------------------
template <int KD, int JD, bool IN_RELU>
__global__ __launch_bounds__(256) void gemm_rt(
    const float* __restrict__ in, const float* __restrict__ W,
    const float* __restrict__ in_bias, const float* __restrict__ out_bias,
    const float* __restrict__ row_scale,
    float* __restrict__ out, int nrows)
{
    __shared__ float Wl[KD * JD];
    __shared__ float F[16 * KD];
    const int t = threadIdx.x;
    for (int i = t; i < KD * JD; i += 256) Wl[i] = W[i];
    const int row0 = blockIdx.x * 16;
    for (int i = t; i < 16 * KD; i += 256) {
        int r = i / KD, k = i % KD;
        float v = 0.f;
        if (row0 + r < nrows) {
            v = in[(long)(row0 + r) * KD + k];
            if (IN_RELU) v = fmaxf(v + in_bias[k], 0.f);
        }
        F[i] = v;
    }
    __syncthreads();
    constexpr int RPF = 256 / JD;
    const int r = t / JD, j = t % JD;
    const float ob = out_bias ? out_bias[j] : 0.f;
    for (int rr = r; rr < 16; rr += RPF) {
        float acc = ob;
        #pragma unroll 16
        for (int k = 0; k < KD; ++k) acc += F[rr * KD + k] * Wl[k * JD + j];
        if (row0 + rr < nrows) {
            float rs = row_scale ? row_scale[row0 + rr] : 1.0f;
            out[(long)(row0 + rr) * JD + j] = acc * rs;
        }
    }
}

// ---------------------------------------------------------------------------
// CSR pull aggregation: o[d,j] = dinv[d] * ( hp[d,j] + sum_{s in N(d)} hp[s,j] )
// hp is already scaled by dinv (done in gemm epilogue). H threads per node.
// ---------------------------------------------------------------------------
template <int H>
__global__ __launch_bounds__(256) void gather_agg_k(
    const float* __restrict__ hp, const int* __restrict__ row_ptr,
    const int* __restrict__ edge_src, const float* __restrict__ dinv,
    float* __restrict__ o, int n)
{
    constexpr int NPB = 256 / H;
    const int node = blockIdx.x * NPB + threadIdx.x / H;
    const int j = threadIdx.x % H;
    if (node >= n) return;
    const int start = row_ptr[node], end = row_ptr[node + 1];
    float acc = hp[(long)node * H + j];
    int e = start;
    for (; e + 4 <= end; e += 4) {
        int s0 = edge_src[e + 0];
        int s1 = edge_src[e + 1];
        int s2 = edge_src[e + 2];
        int s3 = edge_src[e + 3];
        float v0 = hp[(long)s0 * H + j];
        float v1 = hp[(long)s1 * H + j];
        float v2 = hp[(long)s2 * H + j];
        float v3 = hp[(long)s3 * H + j];
        acc += v0 + v1 + v2 + v3;
    }
    for (; e < end; ++e) acc += hp[(long)edge_src[e] * H + j];
    o[(long)node * H + j] = dinv[node] * acc;
}

// ---------------------------------------------------------------------------
extern "C" void kernel_launch(void* const* d_in, const int* in_sizes, int n_in,
                              void* d_out, int out_size, void* d_ws, size_t ws_size,
                              hipStream_t stream) {
    const int*   src     = (const int*)  d_in[0];
    const int*   seg     = (const int*)  d_in[1];
    const int*   ei      = (const int*)  d_in[2];
    const float* src_emb = (const float*)d_in[3];
    const float* seg_emb = (const float*)d_in[4];
    const float* w       = (const float*)d_in[5];
    const float* Wq1     = (const float*)d_in[6];
    const float* bq1     = (const float*)d_in[7];
    const float* Wq2     = (const float*)d_in[8];
    const float* bq2     = (const float*)d_in[9];
    const float* Wg1     = (const float*)d_in[10];
    const float* bg1     = (const float*)d_in[11];
    const float* Wg2     = (const float*)d_in[12];
    const float* bg2     = (const float*)d_in[13];
    const float* Wl      = (const float*)d_in[14];
    const float* bl      = (const float*)d_in[15];
    float* out = (float*)d_out;

    const int N  = in_sizes[0] / 64;
    const int NE = in_sizes[2] / 2;
    const int* si = ei;
    const int* di = ei + NE;

    // workspace layout:
    // int:   cnt[N] | row_ptr[N+1] | cursor[N] | edge_src[NE]
    // float: dinv[N] | f[N*64] | h1[N*128] | o1[N*128]
    // aliases: x=f (mlp in place), h2=f, o2=h1
    char* wsb = (char*)d_ws;
    int* cnt      = (int*)wsb;
    int* row_ptr  = cnt + N;
    int* cursor   = row_ptr + (N + 1);
    int* edge_src = cursor + N;
    float* dinv   = (float*)(edge_src + NE);
    float* f      = dinv + N;
    float* h1     = f  + (size_t)N * 64;
    float* o1     = h1 + (size_t)N * 128;
    float* x      = f;
    float* h2     = f;
    float* o2     = h1;

    dim3 b256(256);
    const int eBlocks = (NE + 255) / 256;

    // CSR build (also produces dinv)
    zero_int_k<<<(N + 255) / 256, b256, 0, stream>>>(cnt, N);
    count_k   <<<eBlocks, b256, 0, stream>>>(di, cnt, NE);
    scan_k    <<<1, 1024, 0, stream>>>(cnt, row_ptr, cursor, dinv, N, NE);
    fill_k    <<<eBlocks, b256, 0, stream>>>(si, di, cursor, edge_src, NE);

    embed_k<<<N, 64, 0, stream>>>(src, seg, src_emb, seg_emb, w, f);

    const int gBlocks = (N + 15) / 16;
    mlp2<<<gBlocks, b256, 0, stream>>>(f, Wq1, bq1, Wq2, bq2, x, N);

    // GCN layer 1: h1 = dinv[r] * (x @ Wg1) ; o1 = dinv*(self + gather)
    gemm_rt<64, 128, false><<<gBlocks, b256, 0, stream>>>(x, Wg1, nullptr, nullptr, dinv, h1, N);
    gather_agg_k<128><<<(N * 128 + 255) / 256, b256, 0, stream>>>(h1, row_ptr, edge_src, dinv, o1, N);

    // GCN layer 2: h2 = dinv[r] * (relu(o1 + bg1) @ Wg2) ; o2 = dinv*(self + gather)
    gemm_rt<128, 64, true><<<gBlocks, b256, 0, stream>>>(o1, Wg2, bg1, nullptr, dinv, h2, N);
    gather_agg_k<64><<<(N * 64 + 255) / 256, b256, 0, stream>>>(h2, row_ptr, edge_src, dinv, o2, N);

    // output: out = relu(o2 + bg2) @ Wl + bl
    gemm_rt<64, 64, true><<<gBlocks, b256, 0, stream>>>(o2, Wl, bg2, bl, nullptr, out, N);
}